// Round 18
// baseline (111.718 us; speedup 1.0000x reference)
//
#include <hip/hip_runtime.h>
#include <math.h>

#define NLAT 360
#define NLON 720
#define LMAX 360
#define MMAX 361
#define KPADC 384   // stage-1 cols per bc: 192 kf x 2 (s)
#define KFP  192    // folded-k padded length (180 data + 12 zero pad)
#define FT_COLS 736
#define FT_ROWS 361
#define NJ   32
#define XST  744
#define YST  72
#define NBLK 192
#define WLS_SH 5440                       // shorts per stage-2 LDS buffer (4*2*17*40)
#define BAR_OFF 531392                    // FT = 361*736*2 = 531,392 B
#define EO_OFF  531456

typedef __attribute__((ext_vector_type(4))) float f32x4;
typedef __attribute__((ext_vector_type(8))) short bf16x8;

__device__ __forceinline__ short f2bf(float f) {
    union { float f; unsigned u; } v; v.f = f;
    unsigned r = (v.u + 0x7FFFu + ((v.u >> 16) & 1u)) >> 16;
    return (short)r;
}

__global__ void init_bar_kernel(unsigned* __restrict__ bar) {
    bar[0] = 0u; bar[1] = 0u;
}

// device-scope grid barrier: single counter + generation; sound because no
// block passes barrier k until all NBLK arrived (reset precedes release).
__device__ __forceinline__ void gbar(unsigned* __restrict__ bar) {
    __syncthreads();
    if (threadIdx.x == 0) {
        __threadfence();
        unsigned g = atomicAdd(&bar[1], 0u);
        unsigned a = atomicAdd(&bar[0], 1u);
        if (a == (unsigned)(NBLK - 1)) {
            atomicExch(&bar[0], 0u);
            __threadfence();
            atomicAdd(&bar[1], 1u);
        } else {
            int guard = 0;
            while (atomicAdd(&bar[1], 0u) == g) {
                __builtin_amdgcn_s_sleep(2);
                if (++guard > 20000000) break;   // breakout: fail visibly, never hang
            }
        }
        __threadfence();
    }
    __syncthreads();
}

// ---------------- stage-2 inner macros (r16 body, LDS base = AuxS+wlb) -----
#define S2_GW(P, T)                                                             \
  { P##wa = *(const f32x4*)(wsp0 + (T) * 32);                                   \
    P##wb = *(const f32x4*)(wsp0 + (T) * 32 + 4);                               \
    P##wc = *(const f32x4*)(wsp1 + (T) * 32);                                   \
    P##wd = *(const f32x4*)(wsp1 + (T) * 32 + 4); }

#define S2_GB(P, T)                                                             \
  { P##ba = *(const bf16x8*)(be0 + (T) * 32);                                   \
    P##bb = *(const bf16x8*)(be1 + (T) * 32);                                   \
    P##bc = *(const bf16x8*)(bo0 + (T) * 32);                                   \
    P##bd = *(const bf16x8*)(bo1 + (T) * 32); }

#define S2_WRT(P, BUF)                                                          \
  { bf16x8 h0, h1;                                                              \
    _Pragma("unroll")                                                           \
    for (int e = 0; e < 4; ++e) {                                               \
      h0[e] = f2bf(P##wa[e]); h0[e + 4] = f2bf(P##wb[e]);                       \
      h1[e] = f2bf(P##wc[e]); h1[e + 4] = f2bf(P##wd[e]);                       \
    }                                                                           \
    *(bf16x8*)&AuxS[wlb + (BUF) * WLS_SH + ldso0] = h0;                         \
    *(bf16x8*)&AuxS[wlb + (BUF) * WLS_SH + ldso1] = h1; }

#define S2_SYNC                                                                 \
    asm volatile("s_waitcnt lgkmcnt(0)" ::: "memory");                          \
    __builtin_amdgcn_s_barrier();                                               \
    __builtin_amdgcn_sched_barrier(0);

#define S2_CMP(P, BUF)                                                          \
  { bf16x8 aEf = *(const bf16x8*)&AuxS[wlb + (BUF) * WLS_SH + aEo];             \
    bf16x8 aOf = *(const bf16x8*)&AuxS[wlb + (BUF) * WLS_SH + aOo];             \
    accE0 = __builtin_amdgcn_mfma_f32_16x16x32_bf16(aEf, P##ba, accE0, 0, 0, 0);\
    accE1 = __builtin_amdgcn_mfma_f32_16x16x32_bf16(aEf, P##bb, accE1, 0, 0, 0);\
    accO0 = __builtin_amdgcn_mfma_f32_16x16x32_bf16(aOf, P##bc, accO0, 0, 0, 0);\
    accO1 = __builtin_amdgcn_mfma_f32_16x16x32_bf16(aOf, P##bd, accO1, 0, 0, 0);}

__global__ __launch_bounds__(512) void mega_kernel(const float* __restrict__ x,
                                                   const float* __restrict__ W,
                                                   float* __restrict__ out,
                                                   char* __restrict__ ws,
                                                   int cm, int nchunks) {
    __shared__ __align__(16) short Xs[64][XST];          // 95,232 B, persists all phases
    __shared__ __align__(16) short AuxS[2 * 2 * WLS_SH]; // 43,520 B: Ys (stage1) / Wl (stage2)

    short*    FT  = (short*)ws;
    unsigned* bar = (unsigned*)(ws + BAR_OFF);
    short*    EO  = (short*)(ws + EO_OFF);

    const int tid8 = threadIdx.x;
    const int blk  = blockIdx.x;

    // ---- phase 0a: FT fill, grid-strided ----
    for (int idx = blk * 512 + tid8; idx < FT_ROWS * FT_COLS; idx += NBLK * 512) {
        const int n = idx % FT_COLS;
        const int m = idx / FT_COLS;
        short val = 0;
        if (n < NLON) {
            int t = (m * n) % NLON;
            float s, c;
            sincospif((float)t / 360.0f, &s, &c);
            val = f2bf((6.283185307179586f / 720.0f) * c);
        }
        FT[idx] = val;
    }

    // ---- phase 0b: x-panel staging into Xs, ONCE ----
    const int col0   = blk * 64;
    const int bc_blk = col0 / KPADC;
    const int kf0    = (col0 - bc_blk * KPADC) >> 1;
    for (int p = tid8; p < 64 * 92; p += 512) {
        const int row = p / 92;
        const int c   = p - row * 92;
        const int gb  = col0 + row;
        const int bc  = gb / KPADC;
        const int q   = gb - bc * KPADC;
        const int kf  = q >> 1;
        const int s   = q & 1;
        const int klat = s ? (NLAT - 1 - kf) : kf;
        f32x4 va = {0,0,0,0}, vb = {0,0,0,0};
        if (c < 90 && kf < 180) {
            const float* xp = x + ((size_t)bc * NLAT + klat) * NLON + c * 8;
            va = *(const f32x4*)xp;
            vb = *(const f32x4*)(xp + 4);
        }
        bf16x8 wv;
        #pragma unroll
        for (int e = 0; e < 4; ++e) { wv[e] = f2bf(va[e]); wv[e + 4] = f2bf(vb[e]); }
        *(bf16x8*)&Xs[row][c * 8] = wv;
    }

    gbar(bar);

    const int wav  = tid8 >> 6;
    const int lane = tid8 & 63;
    const int r    = lane & 15;
    const int kg   = (lane >> 4) * 8;
    const int rowg = (lane >> 4) * 4;

    for (int ck = 0; ck < nchunks; ++ck) {
        const int m0   = ck * cm;
        const int m_hi = (m0 + cm < MMAX) ? (m0 + cm) : MMAX;

        // ================= phase A: stage-1 m-loop (r17 body) =================
        for (int mb = m0; mb < m_hi; mb += 256) {
            const int mwb = mb + wav * 32;
            const bool active = (mwb < m_hi);

            if (active) {
                int mA0 = mwb + r;      if (mA0 > FT_ROWS - 1) mA0 = FT_ROWS - 1;
                int mA1 = mwb + 16 + r; if (mA1 > FT_ROWS - 1) mA1 = FT_ROWS - 1;
                const short* ap0 = FT + (size_t)mA0 * FT_COLS + kg;
                const short* ap1 = FT + (size_t)mA1 * FT_COLS + kg;

                f32x4 acc0[4] = {{0,0,0,0},{0,0,0,0},{0,0,0,0},{0,0,0,0}};
                f32x4 acc1[4] = {{0,0,0,0},{0,0,0,0},{0,0,0,0},{0,0,0,0}};

                bf16x8 A0c = *(const bf16x8*)ap0;
                bf16x8 A1c = *(const bf16x8*)ap1;
                #pragma unroll
                for (int t = 0; t < 23; ++t) {
                    bf16x8 A0n, A1n;
                    if (t < 22) {
                        A0n = *(const bf16x8*)(ap0 + (t + 1) * 32);
                        A1n = *(const bf16x8*)(ap1 + (t + 1) * 32);
                    }
                    #pragma unroll
                    for (int f = 0; f < 4; ++f) {
                        bf16x8 bfr = *(const bf16x8*)&Xs[f * 16 + r][t * 32 + kg];
                        acc0[f] = __builtin_amdgcn_mfma_f32_16x16x32_bf16(A0c, bfr, acc0[f], 0, 0, 0);
                        acc1[f] = __builtin_amdgcn_mfma_f32_16x16x32_bf16(A1c, bfr, acc1[f], 0, 0, 0);
                    }
                    A0c = A0n; A1c = A1n;
                }

                // fold pairs across adjacent lanes, write transposed into Ys(=AuxS)
                #pragma unroll
                for (int f = 0; f < 4; ++f) {
                    const int kfl = (f * 16 + r) >> 1;
                    const int e   = r & 1;
                    const int yo  = e * 32 + kfl;
                    #pragma unroll
                    for (int i = 0; i < 4; ++i) {
                        float v0 = acc0[f][i];
                        float p0 = __shfl_xor(v0, 1);
                        float val0 = e ? (p0 - v0) : (v0 + p0);
                        float v1 = acc1[f][i];
                        float p1 = __shfl_xor(v1, 1);
                        float val1 = e ? (p1 - v1) : (v1 + p1);
                        AuxS[(wav * 32 + rowg + i) * YST + yo]      = f2bf(val0);
                        AuxS[(wav * 32 + 16 + rowg + i) * YST + yo] = f2bf(val1);
                    }
                }
            }
            __syncthreads();

            // coalesced EO store: thread -> (m_loc, e); one full 64B line each
            {
                const int m_loc = tid8 >> 1;
                const int e     = tid8 & 1;
                const int mg    = mb + m_loc;
                if (mg < m_hi) {
                    const short* src = &AuxS[m_loc * YST + e * 32];
                    short* dst = EO + (((size_t)(mg - m0) * 2 + e) * NJ + bc_blk) * KFP + kf0;
                    #pragma unroll
                    for (int j = 0; j < 4; ++j)
                        *(bf16x8*)(dst + j * 8) = *(const bf16x8*)(src + j * 8);
                }
            }
            __syncthreads();
        }

        gbar(bar);   // EO complete & visible

        // ================= phase B: stage-2 (r16 body, 2 halves) =================
        {
            const int tid  = tid8 & 255;
            const int half = tid8 >> 8;
            const int wlb  = half * 2 * WLS_SH;
            const int wavb = tid >> 6;
            const int laneb = tid & 63;
            const int rb   = laneb & 15;
            const int kgb  = (laneb >> 4) * 8;

            const int cmx = m_hi - m0;
            const int gym = (cmx + 3) >> 2;
            int T_c = 0;
            for (int mtt = 0; mtt < gym; ++mtt) T_c += 12 - ((m0 + mtt * 4) >> 5);
            const int niter = (T_c + 2 * NBLK - 1) / (2 * NBLK);

            for (int it = 0; it < niter; ++it) {
                const int tile = blk * 2 + half + it * 2 * NBLK;
                const bool dead = (tile >= T_c);
                int bidd = dead ? 0 : tile;
                int mt = 0;
                for (;;) {
                    const int ccc = 12 - ((m0 + mt * 4) >> 5);
                    if (bidd < ccc) break;
                    bidd -= ccc; ++mt;
                }
                const int ltile = ((m0 + mt * 4) >> 5) + bidd;
                const int l0 = ltile * 32;
                const int mb = m0 + mt * 4;

                const int m    = mb + wavb;
                const int mcl  = (m < m_hi) ? m : (m_hi - 1);
                const int par  = mcl & 1;
                const int mloc = mcl - m0;

                const int srr = tid >> 2;
                const int sq  = (tid & 3) * 8;
                const int moff0 = srr >> 5,        loff0 = srr & 31;
                const int moff1 = (64 + srr) >> 5, loff1 = (64 + srr) & 31;
                int mst0 = mb + moff0; if (mst0 > MMAX - 1) mst0 = MMAX - 1;
                int mst1 = mb + moff1; if (mst1 > MMAX - 1) mst1 = MMAX - 1;
                int lst0 = l0 + loff0; if (lst0 > LMAX - 1) lst0 = LMAX - 1;
                int lst1 = l0 + loff1; if (lst1 > LMAX - 1) lst1 = LMAX - 1;
                const float* wsp0 = W + ((size_t)mst0 * LMAX + lst0) * NLAT + sq;
                const float* wsp1 = W + ((size_t)mst1 * LMAX + lst1) * NLAT + sq;
                const int ldso0 = ((moff0 * 2 + (loff0 & 1)) * 17 + (loff0 >> 1)) * 40 + sq;
                const int ldso1 = ((moff1 * 2 + (loff1 & 1)) * 17 + (loff1 >> 1)) * 40 + sq;

                const short* be0 = EO + (((size_t)mloc * 2 + 0) * NJ + rb)      * KFP + kgb;
                const short* be1 = EO + (((size_t)mloc * 2 + 0) * NJ + 16 + rb) * KFP + kgb;
                const short* bo0 = EO + (((size_t)mloc * 2 + 1) * NJ + rb)      * KFP + kgb;
                const short* bo1 = EO + (((size_t)mloc * 2 + 1) * NJ + 16 + rb) * KFP + kgb;

                const int aEo = ((wavb * 2 + par) * 17 + rb) * 40 + kgb;
                const int aOo = ((wavb * 2 + (1 - par)) * 17 + rb) * 40 + kgb;

                f32x4 accE0 = {0,0,0,0}, accE1 = {0,0,0,0}, accO0 = {0,0,0,0}, accO1 = {0,0,0,0};

                f32x4 Awa, Awb, Awc, Awd, Bwa, Bwb, Bwc, Bwd, Cwa, Cwb, Cwc, Cwd;
                bf16x8 Aba, Abb, Abc, Abd, Bba, Bbb, Bbc, Bbd, Cba, Cbb, Cbc, Cbd;

                S2_GW(A, 0); S2_GB(A, 0);
                S2_GW(B, 1); S2_GB(B, 1);
                S2_GW(C, 2); S2_GB(C, 2);

                S2_WRT(A, 0); S2_SYNC; S2_CMP(A, 0); S2_GW(A, 3); S2_GB(A, 3);
                S2_WRT(B, 1); S2_SYNC; S2_CMP(B, 1); S2_GW(B, 4); S2_GB(B, 4);
                S2_WRT(C, 0); S2_SYNC; S2_CMP(C, 0); S2_GW(C, 5); S2_GB(C, 5);
                S2_WRT(A, 1); S2_SYNC; S2_CMP(A, 1);
                S2_WRT(B, 0); S2_SYNC; S2_CMP(B, 0);
                S2_WRT(C, 1); S2_SYNC; S2_CMP(C, 1);

                const int rowgb = (laneb >> 4) * 4;
                if (m < m_hi && !dead) {
                    #pragma unroll
                    for (int i = 0; i < 4; ++i) {
                        const int R  = rowgb + i;
                        const int le = l0 + par + 2 * R;
                        const int lo = l0 + 1 - par + 2 * R;
                        const size_t b0 = (size_t)rb * LMAX;
                        const size_t b1 = (size_t)(16 + rb) * LMAX;
                        if (le < LMAX) {
                            out[(b0 + le) * MMAX + m] = accE0[i];
                            out[(b1 + le) * MMAX + m] = accE1[i];
                        }
                        if (lo < LMAX) {
                            out[(b0 + lo) * MMAX + m] = accO0[i];
                            out[(b1 + lo) * MMAX + m] = accO1[i];
                        }
                    }
                }
            }
        }

        if (ck + 1 < nchunks) gbar(bar);   // protect EO before next stage-1 pass
    }
}

extern "C" void kernel_launch(void* const* d_in, const int* in_sizes, int n_in,
                              void* d_out, int out_size, void* d_ws, size_t ws_size,
                              hipStream_t stream) {
    const float* x = (const float*)d_in[0];
    const float* w = (const float*)d_in[1];
    float* out = (float*)d_out;
    char* ws = (char*)d_ws;

    const size_t PER_M = (size_t)2 * NJ * KFP * 2;   // 24,576 B per mode
    long cm = 0;
    if (d_ws != nullptr && ws_size > (size_t)EO_OFF + PER_M)
        cm = (long)((ws_size - EO_OFF) / PER_M);
    if (cm > MMAX) cm = MMAX;
    if (cm < 1) return;   // ws proven ~4 MiB; unreachable
    const int nchunks = (MMAX + (int)cm - 1) / (int)cm;

    init_bar_kernel<<<1, 1, 0, stream>>>((unsigned*)(ws + BAR_OFF));
    mega_kernel<<<dim3(NBLK), 512, 0, stream>>>(x, w, out, ws, (int)cm, nchunks);
}

// Round 19
// 69.870 us; speedup vs baseline: 1.5989x; 1.5989x over previous
//
#include <hip/hip_runtime.h>
#include <math.h>

#define NLAT 360
#define NLON 720
#define LMAX 360
#define MMAX 361
#define KPADC 384   // stage-1 cols per bc: 192 kf x 2 (s)
#define KFP  192    // folded-k padded length (180 data + 12 zero pad)
#define FT_COLS 736
#define FT_ROWS_PAD 384
#define NJ   32
#define XST  744
#define YST  72     // Ys row stride (shorts)

typedef __attribute__((ext_vector_type(4))) float f32x4;
typedef __attribute__((ext_vector_type(8))) short bf16x8;

__device__ __forceinline__ short f2bf(float f) {
    union { float f; unsigned u; } v; v.f = f;
    unsigned r = (v.u + 0x7FFFu + ((v.u >> 16) & 1u)) >> 16;
    return (short)r;
}

// ------- kernel 0: bf16 cosine-DFT matrix FT[m][n], pads written as 0 ------
__global__ __launch_bounds__(256) void fill_ft_kernel(short* __restrict__ FT) {
    int idx = blockIdx.x * 256 + threadIdx.x;
    const int total = FT_ROWS_PAD * FT_COLS;
    if (idx >= total) return;
    int n = idx % FT_COLS;
    int m = idx / FT_COLS;
    short val = 0;
    if (m < MMAX && n < NLON) {
        int t = (m * n) % NLON;
        float s, c;
        sincospif((float)t / 360.0f, &s, &c);
        val = f2bf((6.283185307179586f / 720.0f) * c);
    }
    FT[idx] = val;
}

// ---------------- stage 1: x-panel DFT + parity fold (r17 verbatim) --------
__global__ __launch_bounds__(512) void stage1_kernel(const float* __restrict__ x,
                                                     const short* __restrict__ FT,
                                                     short* __restrict__ EO,
                                                     int m0, int cm) {
    __shared__ __align__(16) short Xs[64][XST];     // 95,232 B
    __shared__ __align__(16) short Ys[256 * YST];   // 36,864 B
    const int tid  = threadIdx.x;
    const int wav  = tid >> 6;
    const int lane = tid & 63;
    const int col0 = blockIdx.x * 64;
    const int m_hi = (m0 + cm < MMAX) ? (m0 + cm) : MMAX;

    const int bc_blk = col0 / KPADC;          // 384 % 64 == 0: one bc per block
    const int kf0    = (col0 - bc_blk * KPADC) >> 1;

    for (int p = tid; p < 64 * 92; p += 512) {
        const int row = p / 92;
        const int c   = p - row * 92;
        const int gb  = col0 + row;
        const int bc  = gb / KPADC;
        const int q   = gb - bc * KPADC;
        const int kf  = q >> 1;
        const int s   = q & 1;
        const int klat = s ? (NLAT - 1 - kf) : kf;
        f32x4 va = {0,0,0,0}, vb = {0,0,0,0};
        if (c < 90 && kf < 180) {
            const float* xp = x + ((size_t)bc * NLAT + klat) * NLON + c * 8;
            va = *(const f32x4*)xp;
            vb = *(const f32x4*)(xp + 4);
        }
        bf16x8 wv;
        #pragma unroll
        for (int e = 0; e < 4; ++e) { wv[e] = f2bf(va[e]); wv[e + 4] = f2bf(vb[e]); }
        *(bf16x8*)&Xs[row][c * 8] = wv;
    }
    __syncthreads();

    const int r    = lane & 15;
    const int kg   = (lane >> 4) * 8;
    const int rowg = (lane >> 4) * 4;

    for (int mb = m0; mb < m_hi; mb += 256) {
        const int mwb = mb + wav * 32;
        const bool active = (mwb < m_hi);      // wave-uniform

        if (active) {
            int mA0 = mwb + r;      if (mA0 > FT_ROWS_PAD - 1) mA0 = FT_ROWS_PAD - 1;
            int mA1 = mwb + 16 + r; if (mA1 > FT_ROWS_PAD - 1) mA1 = FT_ROWS_PAD - 1;
            const short* ap0 = FT + (size_t)mA0 * FT_COLS + kg;
            const short* ap1 = FT + (size_t)mA1 * FT_COLS + kg;

            f32x4 acc0[4] = {{0,0,0,0},{0,0,0,0},{0,0,0,0},{0,0,0,0}};
            f32x4 acc1[4] = {{0,0,0,0},{0,0,0,0},{0,0,0,0},{0,0,0,0}};

            bf16x8 A0c = *(const bf16x8*)ap0;
            bf16x8 A1c = *(const bf16x8*)ap1;
            #pragma unroll
            for (int t = 0; t < 23; ++t) {
                bf16x8 A0n, A1n;
                if (t < 22) {
                    A0n = *(const bf16x8*)(ap0 + (t + 1) * 32);
                    A1n = *(const bf16x8*)(ap1 + (t + 1) * 32);
                }
                #pragma unroll
                for (int f = 0; f < 4; ++f) {
                    bf16x8 bfr = *(const bf16x8*)&Xs[f * 16 + r][t * 32 + kg];
                    acc0[f] = __builtin_amdgcn_mfma_f32_16x16x32_bf16(A0c, bfr, acc0[f], 0, 0, 0);
                    acc1[f] = __builtin_amdgcn_mfma_f32_16x16x32_bf16(A1c, bfr, acc1[f], 0, 0, 0);
                }
                A0c = A0n; A1c = A1n;
            }

            // fold pairs across adjacent lanes, write transposed into Ys
            #pragma unroll
            for (int f = 0; f < 4; ++f) {
                const int kfl = (f * 16 + r) >> 1;
                const int e   = r & 1;
                const int yo  = e * 32 + kfl;
                #pragma unroll
                for (int i = 0; i < 4; ++i) {
                    float v0 = acc0[f][i];
                    float p0 = __shfl_xor(v0, 1);
                    float val0 = e ? (p0 - v0) : (v0 + p0);
                    float v1 = acc1[f][i];
                    float p1 = __shfl_xor(v1, 1);
                    float val1 = e ? (p1 - v1) : (v1 + p1);
                    Ys[(wav * 32 + rowg + i) * YST + yo]      = f2bf(val0);
                    Ys[(wav * 32 + 16 + rowg + i) * YST + yo] = f2bf(val1);
                }
            }
        }
        __syncthreads();

        // coalesced EO store: thread -> (m_loc, e); one full 64B line each
        {
            const int m_loc = tid >> 1;
            const int e     = tid & 1;
            const int mg    = mb + m_loc;
            if (mg < m_hi) {
                const short* src = &Ys[m_loc * YST + e * 32];
                short* dst = EO + (((size_t)(mg - m0) * 2 + e) * NJ + bc_blk) * KFP + kf0;
                #pragma unroll
                for (int j = 0; j < 4; ++j)
                    *(bf16x8*)(dst + j * 8) = *(const bf16x8*)(src + j * 8);
            }
        }
        __syncthreads();
    }
}

// ---------------- stage 2: 2-m tiles (620 blocks), counted-vmcnt barriers --
// Block 256 thr = 4 waves = (2 m) x (2 bc-halves); tile 32l x 32bc x 2m.
// Wave: 32l x 16bc x 1m (E+O parity split), K = 6 steps of 32, 3-deep
// register pipeline, ONE raw barrier per step (lgkmcnt only).
#define S2_GW(P, T)                                                             \
  { P##wa = *(const f32x4*)(wsp + (T) * 32);                                    \
    P##wb = *(const f32x4*)(wsp + (T) * 32 + 4); }

#define S2_GB(P, T)                                                             \
  { P##ba = *(const bf16x8*)(be + (T) * 32);                                    \
    P##bc = *(const bf16x8*)(bo + (T) * 32); }

#define S2_WRT(P, BUF)                                                          \
  { bf16x8 h0;                                                                  \
    _Pragma("unroll")                                                           \
    for (int e = 0; e < 4; ++e) {                                               \
      h0[e] = f2bf(P##wa[e]); h0[e + 4] = f2bf(P##wb[e]);                       \
    }                                                                           \
    *(bf16x8*)&Wl[BUF][ldso] = h0; }

#define S2_SYNC                                                                 \
    asm volatile("s_waitcnt lgkmcnt(0)" ::: "memory");                          \
    __builtin_amdgcn_s_barrier();                                               \
    __builtin_amdgcn_sched_barrier(0);

#define S2_CMP(P, BUF)                                                          \
  { bf16x8 aEf = *(const bf16x8*)&Wl[BUF][aEo];                                 \
    bf16x8 aOf = *(const bf16x8*)&Wl[BUF][aOo];                                 \
    accE = __builtin_amdgcn_mfma_f32_16x16x32_bf16(aEf, P##ba, accE, 0, 0, 0);  \
    accO = __builtin_amdgcn_mfma_f32_16x16x32_bf16(aOf, P##bc, accO, 0, 0, 0); }

__global__ __launch_bounds__(256) void stage2_kernel(const float* __restrict__ W,
                                                     const short* __restrict__ EO,
                                                     float* __restrict__ out,
                                                     int m0, int m_hi) {
    __shared__ __align__(16) short Wl[2][2 * 2 * 17 * 40];   // 2 x 5,440 B

    // compacted grid decode: blocks per 2-m tile = 12 - ((m0 + mt*2) >> 5)
    int bid = blockIdx.x;
    int mt = 0;
    for (;;) {
        const int c = 12 - ((m0 + mt * 2) >> 5);
        if (bid < c) break;
        bid -= c; ++mt;
    }
    const int ltile = ((m0 + mt * 2) >> 5) + bid;
    const int l0 = ltile * 32;                  // even
    const int mb = m0 + mt * 2;

    const int tid  = threadIdx.x;
    const int wav  = tid >> 6;                  // 0..3
    const int lane = tid & 63;
    const int r    = lane & 15;
    const int kg   = (lane >> 4) * 8;
    const int m_w  = wav & 1;                   // m offset
    const int bch  = wav >> 1;                  // bc half

    const int m    = mb + m_w;
    const int mc   = (m < m_hi) ? m : (m_hi - 1);
    const int par  = mc & 1;
    const int mloc = mc - m0;

    // staging: 64 rows (2m x 32l) x 32k per step; 4 threads/row, 8 floats each
    const int srow = tid >> 2;                  // 0..63
    const int sq   = (tid & 3) * 8;             // k offset (floats)
    const int m_s  = srow >> 5, l_s = srow & 31;
    int mst = mb + m_s; if (mst > MMAX - 1) mst = MMAX - 1;
    int lst = l0 + l_s; if (lst > LMAX - 1) lst = LMAX - 1;
    const float* wsp = W + ((size_t)mst * LMAX + lst) * NLAT + sq;
    const int ldso = ((m_s * 2 + (l_s & 1)) * 17 + (l_s >> 1)) * 40 + sq;

    // B pointers (EO, per-lane; L2/L3-resident)
    const short* be = EO + (((size_t)mloc * 2 + 0) * NJ + bch * 16 + r) * KFP + kg;
    const short* bo = EO + (((size_t)mloc * 2 + 1) * NJ + bch * 16 + r) * KFP + kg;

    // A fragment LDS offsets
    const int aEo = ((m_w * 2 + par) * 17 + r) * 40 + kg;
    const int aOo = ((m_w * 2 + (1 - par)) * 17 + r) * 40 + kg;

    f32x4 accE = {0,0,0,0}, accO = {0,0,0,0};

    f32x4 Awa, Awb, Bwa, Bwb, Cwa, Cwb;
    bf16x8 Aba, Abc, Bba, Bbc, Cba, Cbc;

    // prologue: 3 K-steps in flight
    S2_GW(A, 0); S2_GB(A, 0);
    S2_GW(B, 1); S2_GB(B, 1);
    S2_GW(C, 2); S2_GB(C, 2);

    S2_WRT(A, 0); S2_SYNC; S2_CMP(A, 0); S2_GW(A, 3); S2_GB(A, 3);
    S2_WRT(B, 1); S2_SYNC; S2_CMP(B, 1); S2_GW(B, 4); S2_GB(B, 4);
    S2_WRT(C, 0); S2_SYNC; S2_CMP(C, 0); S2_GW(C, 5); S2_GB(C, 5);
    S2_WRT(A, 1); S2_SYNC; S2_CMP(A, 1);
    S2_WRT(B, 0); S2_SYNC; S2_CMP(B, 0);
    S2_WRT(C, 1); S2_SYNC; S2_CMP(C, 1);

    // epilogue: wave (m_w, bch): col bc = bch*16 + r; row R -> l parity split
    const int rowg = (lane >> 4) * 4;
    if (m < m_hi) {
        const int bcc = bch * 16 + r;
        const size_t base = (size_t)bcc * LMAX;
        #pragma unroll
        for (int i = 0; i < 4; ++i) {
            const int R  = rowg + i;
            const int le = l0 + par + 2 * R;
            const int lo = l0 + 1 - par + 2 * R;
            if (le < LMAX) out[(base + le) * MMAX + m] = accE[i];
            if (lo < LMAX) out[(base + lo) * MMAX + m] = accO[i];
        }
    }
}

extern "C" void kernel_launch(void* const* d_in, const int* in_sizes, int n_in,
                              void* d_out, int out_size, void* d_ws, size_t ws_size,
                              hipStream_t stream) {
    const float* x = (const float*)d_in[0];
    const float* w = (const float*)d_in[1];
    float* out = (float*)d_out;

    const size_t XR_OFF = (size_t)FT_ROWS_PAD * FT_COLS * 2;  // 565,248 B
    const size_t PER_M  = (size_t)2 * NJ * KFP * 2;           // 24,576 B per mode
    long cm = 0;
    if (d_ws != nullptr && ws_size > XR_OFF + PER_M) cm = (long)((ws_size - XR_OFF) / PER_M);
    if (cm > MMAX) cm = MMAX;
    if (cm < 1) return;

    short* FT = (short*)d_ws;
    short* EO = (short*)((char*)d_ws + XR_OFF);
    fill_ft_kernel<<<(FT_ROWS_PAD * FT_COLS + 255) / 256, 256, 0, stream>>>(FT);
    for (int m0 = 0; m0 < MMAX; m0 += (int)cm) {
        const int cmx = ((int)cm < MMAX - m0) ? (int)cm : (MMAX - m0);
        stage1_kernel<<<dim3(192), 512, 0, stream>>>(x, FT, EO, m0, cmx);
        const int gym = (cmx + 1) / 2;
        int nblk = 0;
        for (int mtt = 0; mtt < gym; ++mtt) nblk += 12 - ((m0 + mtt * 2) >> 5);
        stage2_kernel<<<dim3(nblk), 256, 0, stream>>>(w, EO, out, m0, m0 + cmx);
    }
}

// Round 20
// 64.463 us; speedup vs baseline: 1.7330x; 1.0839x over previous
//
#include <hip/hip_runtime.h>
#include <math.h>

#define NLAT 360
#define NLON 720
#define LMAX 360
#define MMAX 361
#define KPADC 384   // stage-1 C-col space per bc: 192 kf x 2 (s)
#define KFP  192    // folded-k padded length (180 data + 12 zero pad)
#define FT2C 384    // n-folded DFT cols (360 data + 24 zero pad)
#define FT2R 368    // FT2 rows (361 data + 7 zero pad)
#define NJ   32
#define PS   392    // Xs col stride (shorts): dword-stride 196 = 4 mod 32 -> 2-way banks
#define YST  72     // Ys row stride (shorts)

typedef __attribute__((ext_vector_type(4))) float f32x4;
typedef __attribute__((ext_vector_type(8))) short bf16x8;

__device__ __forceinline__ short f2bf(float f) {
    union { float f; unsigned u; } v; v.f = f;
    unsigned r = (v.u + 0x7FFFu + ((v.u >> 16) & 1u)) >> 16;
    return (short)r;
}

// --- kernel 0: n-folded bf16 cosine-DFT matrix FT2[m][n'], pads = 0 --------
// FT2[m][n'] = (2pi/720)*cos(2pi*m*n'/720), n' in [0,360); x-fold supplies
// the (-1)^m factor for n >= 360 (even m read sum-plane, odd m diff-plane).
__global__ __launch_bounds__(256) void fill_ft_kernel(short* __restrict__ FT2) {
    int idx = blockIdx.x * 256 + threadIdx.x;
    const int total = FT2R * FT2C;
    if (idx >= total) return;
    int n = idx % FT2C;
    int m = idx / FT2C;
    short val = 0;
    if (m < MMAX && n < 360) {
        int t = (m * n) % NLON;
        float s, c;
        sincospif((float)t / 360.0f, &s, &c);
        val = f2bf((6.283185307179586f / 720.0f) * c);
    }
    FT2[idx] = val;
}

// ---------------- stage 1: x-panel DFT, n-fold + k-fold --------------------
// Staging: Xs[plane][col][n'] with xs = x[n']+x[n'+360], xd = x[n']-x[n'+360].
// Compute: 12 K-steps; even-m row-set x sum-plane, odd-m row-set x diff-plane.
// Epilogue (k-fold + Ys transpose + coalesced EO store) identical to r17.
__global__ __launch_bounds__(512) void stage1_kernel(const float* __restrict__ x,
                                                     const short* __restrict__ FT2,
                                                     short* __restrict__ EO,
                                                     int m0, int cm) {
    __shared__ __align__(16) short Xs[2][64][PS];   // 100,352 B
    __shared__ __align__(16) short Ys[256 * YST];   // 36,864 B
    const int tid  = threadIdx.x;
    const int wav  = tid >> 6;
    const int lane = tid & 63;
    const int col0 = blockIdx.x * 64;
    const int m_hi = (m0 + cm < MMAX) ? (m0 + cm) : MMAX;

    const int bc_blk = col0 / KPADC;          // 384 % 64 == 0: one bc per block
    const int kf0    = (col0 - bc_blk * KPADC) >> 1;

    // staging: 64 rows x 48 chunks of 8 n' (45 data chunks + 3 zero-pad)
    for (int p = tid; p < 64 * 48; p += 512) {
        const int row = p / 48;
        const int c   = p - row * 48;
        const int gb  = col0 + row;
        const int bc  = gb / KPADC;
        const int q   = gb - bc * KPADC;
        const int kf  = q >> 1;
        const int s   = q & 1;
        const int klat = s ? (NLAT - 1 - kf) : kf;
        f32x4 a0 = {0,0,0,0}, a1 = {0,0,0,0}, b0 = {0,0,0,0}, b1 = {0,0,0,0};
        if (c < 45 && kf < 180) {
            const float* xp = x + ((size_t)bc * NLAT + klat) * NLON + c * 8;
            a0 = *(const f32x4*)xp;
            a1 = *(const f32x4*)(xp + 4);
            b0 = *(const f32x4*)(xp + 360);
            b1 = *(const f32x4*)(xp + 364);
        }
        bf16x8 sv, dv;
        #pragma unroll
        for (int e = 0; e < 4; ++e) {
            sv[e]     = f2bf(a0[e] + b0[e]);
            sv[e + 4] = f2bf(a1[e] + b1[e]);
            dv[e]     = f2bf(a0[e] - b0[e]);
            dv[e + 4] = f2bf(a1[e] - b1[e]);
        }
        *(bf16x8*)&Xs[0][row][c * 8] = sv;
        *(bf16x8*)&Xs[1][row][c * 8] = dv;
    }
    __syncthreads();

    const int r    = lane & 15;
    const int kg   = (lane >> 4) * 8;
    const int rowg = (lane >> 4) * 4;

    for (int mb = m0; mb < m_hi; mb += 256) {
        const int mwb = mb + wav * 32;
        const bool active = (mwb < m_hi);      // wave-uniform

        if (active) {
            int mE = mwb + 2 * r;     if (mE > FT2R - 1) mE = FT2R - 1;   // pad rows are 0
            int mO = mwb + 2 * r + 1; if (mO > FT2R - 1) mO = FT2R - 1;
            const short* ape = FT2 + (size_t)mE * FT2C + kg;
            const short* apo = FT2 + (size_t)mO * FT2C + kg;

            f32x4 accE[4] = {{0,0,0,0},{0,0,0,0},{0,0,0,0},{0,0,0,0}};
            f32x4 accO[4] = {{0,0,0,0},{0,0,0,0},{0,0,0,0},{0,0,0,0}};

            bf16x8 AEc = *(const bf16x8*)ape;
            bf16x8 AOc = *(const bf16x8*)apo;
            #pragma unroll
            for (int t = 0; t < 12; ++t) {
                bf16x8 AEn, AOn;
                if (t < 11) {
                    AEn = *(const bf16x8*)(ape + (t + 1) * 32);
                    AOn = *(const bf16x8*)(apo + (t + 1) * 32);
                }
                #pragma unroll
                for (int f = 0; f < 4; ++f) {
                    bf16x8 bS = *(const bf16x8*)&Xs[0][f * 16 + r][t * 32 + kg];
                    bf16x8 bD = *(const bf16x8*)&Xs[1][f * 16 + r][t * 32 + kg];
                    accE[f] = __builtin_amdgcn_mfma_f32_16x16x32_bf16(AEc, bS, accE[f], 0, 0, 0);
                    accO[f] = __builtin_amdgcn_mfma_f32_16x16x32_bf16(AOc, bD, accO[f], 0, 0, 0);
                }
                AEc = AEn; AOc = AOn;
            }

            // k-fold across adjacent lanes; Ys rows m_loc = wav*32 + 2R (+1)
            #pragma unroll
            for (int f = 0; f < 4; ++f) {
                const int kfl = (f * 16 + r) >> 1;
                const int e   = r & 1;
                const int yo  = e * 32 + kfl;
                #pragma unroll
                for (int i = 0; i < 4; ++i) {
                    float vE = accE[f][i];
                    float pE = __shfl_xor(vE, 1);
                    float valE = e ? (pE - vE) : (vE + pE);
                    float vO = accO[f][i];
                    float pO = __shfl_xor(vO, 1);
                    float valO = e ? (pO - vO) : (vO + pO);
                    const int mlE = wav * 32 + 2 * (rowg + i);
                    Ys[(size_t)mlE * YST + yo]       = f2bf(valE);
                    Ys[(size_t)(mlE + 1) * YST + yo] = f2bf(valO);
                }
            }
        }
        __syncthreads();

        // coalesced EO store: thread -> (m_loc, e); one full 64B line each
        {
            const int m_loc = tid >> 1;
            const int e     = tid & 1;
            const int mg    = mb + m_loc;
            if (mg < m_hi) {
                const short* src = &Ys[m_loc * YST + e * 32];
                short* dst = EO + (((size_t)(mg - m0) * 2 + e) * NJ + bc_blk) * KFP + kf0;
                #pragma unroll
                for (int j = 0; j < 4; ++j)
                    *(bf16x8*)(dst + j * 8) = *(const bf16x8*)(src + j * 8);
            }
        }
        __syncthreads();
    }
}

// ---------------- stage 2: r17 champion verbatim (4-m tiles, 3-deep) -------
#define S2_GW(P, T)                                                             \
  { P##wa = *(const f32x4*)(wsp0 + (T) * 32);                                   \
    P##wb = *(const f32x4*)(wsp0 + (T) * 32 + 4);                               \
    P##wc = *(const f32x4*)(wsp1 + (T) * 32);                                   \
    P##wd = *(const f32x4*)(wsp1 + (T) * 32 + 4); }

#define S2_GB(P, T)                                                             \
  { P##ba = *(const bf16x8*)(be0 + (T) * 32);                                   \
    P##bb = *(const bf16x8*)(be1 + (T) * 32);                                   \
    P##bc = *(const bf16x8*)(bo0 + (T) * 32);                                   \
    P##bd = *(const bf16x8*)(bo1 + (T) * 32); }

#define S2_WRT(P, BUF)                                                          \
  { bf16x8 h0, h1;                                                              \
    _Pragma("unroll")                                                           \
    for (int e = 0; e < 4; ++e) {                                               \
      h0[e] = f2bf(P##wa[e]); h0[e + 4] = f2bf(P##wb[e]);                       \
      h1[e] = f2bf(P##wc[e]); h1[e + 4] = f2bf(P##wd[e]);                       \
    }                                                                           \
    *(bf16x8*)&Wl[BUF][ldso0] = h0;                                             \
    *(bf16x8*)&Wl[BUF][ldso1] = h1; }

#define S2_SYNC                                                                 \
    asm volatile("s_waitcnt lgkmcnt(0)" ::: "memory");                          \
    __builtin_amdgcn_s_barrier();                                               \
    __builtin_amdgcn_sched_barrier(0);

#define S2_CMP(P, BUF)                                                          \
  { bf16x8 aEf = *(const bf16x8*)&Wl[BUF][aEo];                                 \
    bf16x8 aOf = *(const bf16x8*)&Wl[BUF][aOo];                                 \
    accE0 = __builtin_amdgcn_mfma_f32_16x16x32_bf16(aEf, P##ba, accE0, 0, 0, 0);\
    accE1 = __builtin_amdgcn_mfma_f32_16x16x32_bf16(aEf, P##bb, accE1, 0, 0, 0);\
    accO0 = __builtin_amdgcn_mfma_f32_16x16x32_bf16(aOf, P##bc, accO0, 0, 0, 0);\
    accO1 = __builtin_amdgcn_mfma_f32_16x16x32_bf16(aOf, P##bd, accO1, 0, 0, 0);}

__global__ __launch_bounds__(256) void stage2_kernel(const float* __restrict__ W,
                                                     const short* __restrict__ EO,
                                                     float* __restrict__ out,
                                                     int m0, int m_hi) {
    __shared__ __align__(16) short Wl[2][4 * 2 * 17 * 40];   // 2 x 10,880 B

    int bid = blockIdx.x;
    int mt = 0;
    for (;;) {
        const int c = 12 - ((m0 + mt * 4) >> 5);
        if (bid < c) break;
        bid -= c; ++mt;
    }
    const int ltile = ((m0 + mt * 4) >> 5) + bid;
    const int l0 = ltile * 32;                  // even
    const int mb = m0 + mt * 4;

    const int tid  = threadIdx.x;
    const int wav  = tid >> 6;                  // 0..3 = m offset
    const int lane = tid & 63;
    const int r    = lane & 15;
    const int kg   = (lane >> 4) * 8;

    const int m    = mb + wav;
    const int mc   = (m < m_hi) ? m : (m_hi - 1);
    const int par  = mc & 1;
    const int mloc = mc - m0;

    const int srr = tid >> 2;
    const int sq  = (tid & 3) * 8;
    const int moff0 = srr >> 5,        loff0 = srr & 31;
    const int moff1 = (64 + srr) >> 5, loff1 = (64 + srr) & 31;
    int mst0 = mb + moff0; if (mst0 > MMAX - 1) mst0 = MMAX - 1;
    int mst1 = mb + moff1; if (mst1 > MMAX - 1) mst1 = MMAX - 1;
    int lst0 = l0 + loff0; if (lst0 > LMAX - 1) lst0 = LMAX - 1;
    int lst1 = l0 + loff1; if (lst1 > LMAX - 1) lst1 = LMAX - 1;
    const float* wsp0 = W + ((size_t)mst0 * LMAX + lst0) * NLAT + sq;
    const float* wsp1 = W + ((size_t)mst1 * LMAX + lst1) * NLAT + sq;
    const int ldso0 = ((moff0 * 2 + (loff0 & 1)) * 17 + (loff0 >> 1)) * 40 + sq;
    const int ldso1 = ((moff1 * 2 + (loff1 & 1)) * 17 + (loff1 >> 1)) * 40 + sq;

    const short* be0 = EO + (((size_t)mloc * 2 + 0) * NJ + r)      * KFP + kg;
    const short* be1 = EO + (((size_t)mloc * 2 + 0) * NJ + 16 + r) * KFP + kg;
    const short* bo0 = EO + (((size_t)mloc * 2 + 1) * NJ + r)      * KFP + kg;
    const short* bo1 = EO + (((size_t)mloc * 2 + 1) * NJ + 16 + r) * KFP + kg;

    const int aEo = ((wav * 2 + par) * 17 + r) * 40 + kg;
    const int aOo = ((wav * 2 + (1 - par)) * 17 + r) * 40 + kg;

    f32x4 accE0 = {0,0,0,0}, accE1 = {0,0,0,0}, accO0 = {0,0,0,0}, accO1 = {0,0,0,0};

    f32x4 Awa, Awb, Awc, Awd, Bwa, Bwb, Bwc, Bwd, Cwa, Cwb, Cwc, Cwd;
    bf16x8 Aba, Abb, Abc, Abd, Bba, Bbb, Bbc, Bbd, Cba, Cbb, Cbc, Cbd;

    S2_GW(A, 0); S2_GB(A, 0);
    S2_GW(B, 1); S2_GB(B, 1);
    S2_GW(C, 2); S2_GB(C, 2);

    S2_WRT(A, 0); S2_SYNC; S2_CMP(A, 0); S2_GW(A, 3); S2_GB(A, 3);
    S2_WRT(B, 1); S2_SYNC; S2_CMP(B, 1); S2_GW(B, 4); S2_GB(B, 4);
    S2_WRT(C, 0); S2_SYNC; S2_CMP(C, 0); S2_GW(C, 5); S2_GB(C, 5);
    S2_WRT(A, 1); S2_SYNC; S2_CMP(A, 1);
    S2_WRT(B, 0); S2_SYNC; S2_CMP(B, 0);
    S2_WRT(C, 1); S2_SYNC; S2_CMP(C, 1);

    const int rowg = (lane >> 4) * 4;
    if (m < m_hi) {
        #pragma unroll
        for (int i = 0; i < 4; ++i) {
            const int R  = rowg + i;
            const int le = l0 + par + 2 * R;
            const int lo = l0 + 1 - par + 2 * R;
            const size_t b0 = (size_t)r * LMAX;
            const size_t b1 = (size_t)(16 + r) * LMAX;
            if (le < LMAX) {
                out[(b0 + le) * MMAX + m] = accE0[i];
                out[(b1 + le) * MMAX + m] = accE1[i];
            }
            if (lo < LMAX) {
                out[(b0 + lo) * MMAX + m] = accO0[i];
                out[(b1 + lo) * MMAX + m] = accO1[i];
            }
        }
    }
}

extern "C" void kernel_launch(void* const* d_in, const int* in_sizes, int n_in,
                              void* d_out, int out_size, void* d_ws, size_t ws_size,
                              hipStream_t stream) {
    const float* x = (const float*)d_in[0];
    const float* w = (const float*)d_in[1];
    float* out = (float*)d_out;

    const size_t XR_OFF = (size_t)FT2R * FT2C * 2;   // 282,624 B
    const size_t PER_M  = (size_t)2 * NJ * KFP * 2;  // 24,576 B per mode
    long cm = 0;
    if (d_ws != nullptr && ws_size > XR_OFF + PER_M) cm = (long)((ws_size - XR_OFF) / PER_M);
    if (cm > MMAX) cm = MMAX;
    if (cm < 1) return;

    short* FT2 = (short*)d_ws;
    short* EO  = (short*)((char*)d_ws + XR_OFF);
    fill_ft_kernel<<<(FT2R * FT2C + 255) / 256, 256, 0, stream>>>(FT2);
    for (int m0 = 0; m0 < MMAX; m0 += (int)cm) {
        const int cmx = ((int)cm < MMAX - m0) ? (int)cm : (MMAX - m0);
        stage1_kernel<<<dim3(192), 512, 0, stream>>>(x, FT2, EO, m0, cmx);
        const int gym = (cmx + 3) / 4;
        int nblk = 0;
        for (int mtt = 0; mtt < gym; ++mtt) nblk += 12 - ((m0 + mtt * 4) >> 5);
        stage2_kernel<<<dim3(nblk), 256, 0, stream>>>(w, EO, out, m0, m0 + cmx);
    }
}

// Round 21
// 60.933 us; speedup vs baseline: 1.8335x; 1.0579x over previous
//
#include <hip/hip_runtime.h>
#include <math.h>

#define NLAT 360
#define NLON 720
#define LMAX 360
#define MMAX 361
#define KPADC 384   // stage-1 C-col space per bc: 192 kf x 2 (s)
#define KFP  192    // folded-k padded length (180 data + 12 zero pad)
#define FT2C 192    // radix-4 folded DFT cols (181 data + 11 zero pad)
#define FT2R 368    // FT rows (361 data + 7 zero pad)
#define NJ   32
#define PS   200    // Xs col stride (shorts): 100 dwords = 4 mod 32 -> 2-way banks
#define YST  72     // Ys row stride (shorts)

typedef __attribute__((ext_vector_type(4))) float f32x4;
typedef __attribute__((ext_vector_type(8))) short bf16x8;

__device__ __forceinline__ short f2bf(float f) {
    union { float f; unsigned u; } v; v.f = f;
    unsigned r = (v.u + 0x7FFFu + ((v.u >> 16) & 1u)) >> 16;
    return (short)r;
}

// --- kernel 0: radix-4 folded bf16 cosine-DFT matrix FT[m][n3], pads = 0 ---
// FT[m][n3] = (2pi/720)*cos(2pi*m*n3/720), n3 in [0,180]; the x-folds supply
// (-1)^m for n>=360 and the n' <-> 360-n' symmetry (even m: +, odd m: -).
__global__ __launch_bounds__(256) void fill_ft_kernel(short* __restrict__ FT2) {
    int idx = blockIdx.x * 256 + threadIdx.x;
    const int total = FT2R * FT2C;
    if (idx >= total) return;
    int n = idx % FT2C;
    int m = idx / FT2C;
    short val = 0;
    if (m < MMAX && n <= 180) {
        int t = (m * n) % NLON;
        float s, c;
        sincospif((float)t / 360.0f, &s, &c);
        val = f2bf((6.283185307179586f / 720.0f) * c);
    }
    FT2[idx] = val;
}

// ---------------- stage 1: x-panel DFT, radix-4 n-fold + k-fold ------------
// Staging: plane0[n3] = (x[n3]+x[n3+360]) + (x[360-n3]+x[720-n3])  (even m)
//          plane1[n3] = (x[n3]-x[n3+360]) - (x[360-n3]-x[720-n3])  (odd m)
// n3 in [0,180], unpaired edges n3=0,180 carry no reverse term.
// Compute: 6 K-steps; even-m rows x plane0, odd-m rows x plane1.
// Epilogue (k-fold + Ys transpose + coalesced EO store) identical to r17-r20.
__global__ __launch_bounds__(512) void stage1_kernel(const float* __restrict__ x,
                                                     const short* __restrict__ FT2,
                                                     short* __restrict__ EO,
                                                     int m0, int cm) {
    __shared__ __align__(16) short Xs[2][64][PS];   // 51,200 B
    __shared__ __align__(16) short Ys[256 * YST];   // 36,864 B
    const int tid  = threadIdx.x;
    const int wav  = tid >> 6;
    const int lane = tid & 63;
    const int col0 = blockIdx.x * 64;
    const int m_hi = (m0 + cm < MMAX) ? (m0 + cm) : MMAX;

    const int bc_blk = col0 / KPADC;          // 384 % 64 == 0: one bc per block
    const int kf0    = (col0 - bc_blk * KPADC) >> 1;

    // staging: 64 rows x 24 chunks of 8 n3 (181 data + 11 zero-pad cols)
    for (int p = tid; p < 64 * 24; p += 512) {
        const int row = p / 24;
        const int c   = p - row * 24;
        const int gb  = col0 + row;
        const int bc  = gb / KPADC;
        const int q   = gb - bc * KPADC;
        const int kf  = q >> 1;
        const int s   = q & 1;
        const int klat = s ? (NLAT - 1 - kf) : kf;
        bf16x8 sv = {0,0,0,0,0,0,0,0}, dv = {0,0,0,0,0,0,0,0};
        if (kf < 180) {
            const float* xp = x + ((size_t)bc * NLAT + klat) * NLON;
            const int n0 = c * 8;
            f32x4 f0 = *(const f32x4*)(xp + n0);
            f32x4 f1 = *(const f32x4*)(xp + n0 + 4);
            f32x4 g0 = *(const f32x4*)(xp + n0 + 360);
            f32x4 g1 = *(const f32x4*)(xp + n0 + 364);
            // reverse windows (16B-aligned): v[j]=x[352-n0+j], w[j]=x[712-n0+j]
            f32x4 v0 = *(const f32x4*)(xp + 352 - n0);
            f32x4 v1 = *(const f32x4*)(xp + 356 - n0);
            f32x4 w0 = *(const f32x4*)(xp + 712 - n0);
            f32x4 w1 = *(const f32x4*)(xp + 716 - n0);
            const float t360 = xp[360 - n0];
            const float t720 = (c > 0) ? xp[720 - n0] : 0.0f;  // c==0: masked below
            #pragma unroll
            for (int e = 0; e < 8; ++e) {
                const int n3 = n0 + e;
                const float a = (e < 4) ? f0[e] : f1[e - 4];
                const float b = (e < 4) ? g0[e] : g1[e - 4];
                // x[360-n3]: e==0 -> t360, else v[8-e]; x[720-n3]: e==0 -> t720, else w[8-e]
                float r3 = (e == 0) ? t360 : ((8 - e < 4) ? v0[(8 - e) & 3] : v1[(8 - e) & 3]);
                float r7 = (e == 0) ? t720 : ((8 - e < 4) ? w0[(8 - e) & 3] : w1[(8 - e) & 3]);
                if (n3 == 0 || n3 == 180) { r3 = 0.0f; r7 = 0.0f; }   // unpaired edges
                sv[e] = f2bf((a + b) + (r3 + r7));
                dv[e] = f2bf((a - b) - (r3 - r7));
            }
        }
        *(bf16x8*)&Xs[0][row][c * 8] = sv;
        *(bf16x8*)&Xs[1][row][c * 8] = dv;
    }
    __syncthreads();

    const int r    = lane & 15;
    const int kg   = (lane >> 4) * 8;
    const int rowg = (lane >> 4) * 4;

    for (int mb = m0; mb < m_hi; mb += 256) {
        const int mwb = mb + wav * 32;
        const bool active = (mwb < m_hi);      // wave-uniform

        if (active) {
            int mE = mwb + 2 * r;     if (mE > FT2R - 1) mE = FT2R - 1;   // pad rows are 0
            int mO = mwb + 2 * r + 1; if (mO > FT2R - 1) mO = FT2R - 1;
            const short* ape = FT2 + (size_t)mE * FT2C + kg;
            const short* apo = FT2 + (size_t)mO * FT2C + kg;

            f32x4 accE[4] = {{0,0,0,0},{0,0,0,0},{0,0,0,0},{0,0,0,0}};
            f32x4 accO[4] = {{0,0,0,0},{0,0,0,0},{0,0,0,0},{0,0,0,0}};

            bf16x8 AEc = *(const bf16x8*)ape;
            bf16x8 AOc = *(const bf16x8*)apo;
            #pragma unroll
            for (int t = 0; t < 6; ++t) {
                bf16x8 AEn, AOn;
                if (t < 5) {
                    AEn = *(const bf16x8*)(ape + (t + 1) * 32);
                    AOn = *(const bf16x8*)(apo + (t + 1) * 32);
                }
                #pragma unroll
                for (int f = 0; f < 4; ++f) {
                    bf16x8 bS = *(const bf16x8*)&Xs[0][f * 16 + r][t * 32 + kg];
                    bf16x8 bD = *(const bf16x8*)&Xs[1][f * 16 + r][t * 32 + kg];
                    accE[f] = __builtin_amdgcn_mfma_f32_16x16x32_bf16(AEc, bS, accE[f], 0, 0, 0);
                    accO[f] = __builtin_amdgcn_mfma_f32_16x16x32_bf16(AOc, bD, accO[f], 0, 0, 0);
                }
                AEc = AEn; AOc = AOn;
            }

            // k-fold across adjacent lanes; Ys rows m_loc = wav*32 + 2R (+1)
            #pragma unroll
            for (int f = 0; f < 4; ++f) {
                const int kfl = (f * 16 + r) >> 1;
                const int e   = r & 1;
                const int yo  = e * 32 + kfl;
                #pragma unroll
                for (int i = 0; i < 4; ++i) {
                    float vE = accE[f][i];
                    float pE = __shfl_xor(vE, 1);
                    float valE = e ? (pE - vE) : (vE + pE);
                    float vO = accO[f][i];
                    float pO = __shfl_xor(vO, 1);
                    float valO = e ? (pO - vO) : (vO + pO);
                    const int mlE = wav * 32 + 2 * (rowg + i);
                    Ys[(size_t)mlE * YST + yo]       = f2bf(valE);
                    Ys[(size_t)(mlE + 1) * YST + yo] = f2bf(valO);
                }
            }
        }
        __syncthreads();

        // coalesced EO store: thread -> (m_loc, e); one full 64B line each
        {
            const int m_loc = tid >> 1;
            const int e     = tid & 1;
            const int mg    = mb + m_loc;
            if (mg < m_hi) {
                const short* src = &Ys[m_loc * YST + e * 32];
                short* dst = EO + (((size_t)(mg - m0) * 2 + e) * NJ + bc_blk) * KFP + kf0;
                #pragma unroll
                for (int j = 0; j < 4; ++j)
                    *(bf16x8*)(dst + j * 8) = *(const bf16x8*)(src + j * 8);
            }
        }
        __syncthreads();
    }
}

// ---------------- stage 2: r17-r20 champion verbatim (4-m tiles, 3-deep) ---
#define S2_GW(P, T)                                                             \
  { P##wa = *(const f32x4*)(wsp0 + (T) * 32);                                   \
    P##wb = *(const f32x4*)(wsp0 + (T) * 32 + 4);                               \
    P##wc = *(const f32x4*)(wsp1 + (T) * 32);                                   \
    P##wd = *(const f32x4*)(wsp1 + (T) * 32 + 4); }

#define S2_GB(P, T)                                                             \
  { P##ba = *(const bf16x8*)(be0 + (T) * 32);                                   \
    P##bb = *(const bf16x8*)(be1 + (T) * 32);                                   \
    P##bc = *(const bf16x8*)(bo0 + (T) * 32);                                   \
    P##bd = *(const bf16x8*)(bo1 + (T) * 32); }

#define S2_WRT(P, BUF)                                                          \
  { bf16x8 h0, h1;                                                              \
    _Pragma("unroll")                                                           \
    for (int e = 0; e < 4; ++e) {                                               \
      h0[e] = f2bf(P##wa[e]); h0[e + 4] = f2bf(P##wb[e]);                       \
      h1[e] = f2bf(P##wc[e]); h1[e + 4] = f2bf(P##wd[e]);                       \
    }                                                                           \
    *(bf16x8*)&Wl[BUF][ldso0] = h0;                                             \
    *(bf16x8*)&Wl[BUF][ldso1] = h1; }

#define S2_SYNC                                                                 \
    asm volatile("s_waitcnt lgkmcnt(0)" ::: "memory");                          \
    __builtin_amdgcn_s_barrier();                                               \
    __builtin_amdgcn_sched_barrier(0);

#define S2_CMP(P, BUF)                                                          \
  { bf16x8 aEf = *(const bf16x8*)&Wl[BUF][aEo];                                 \
    bf16x8 aOf = *(const bf16x8*)&Wl[BUF][aOo];                                 \
    accE0 = __builtin_amdgcn_mfma_f32_16x16x32_bf16(aEf, P##ba, accE0, 0, 0, 0);\
    accE1 = __builtin_amdgcn_mfma_f32_16x16x32_bf16(aEf, P##bb, accE1, 0, 0, 0);\
    accO0 = __builtin_amdgcn_mfma_f32_16x16x32_bf16(aOf, P##bc, accO0, 0, 0, 0);\
    accO1 = __builtin_amdgcn_mfma_f32_16x16x32_bf16(aOf, P##bd, accO1, 0, 0, 0);}

__global__ __launch_bounds__(256) void stage2_kernel(const float* __restrict__ W,
                                                     const short* __restrict__ EO,
                                                     float* __restrict__ out,
                                                     int m0, int m_hi) {
    __shared__ __align__(16) short Wl[2][4 * 2 * 17 * 40];   // 2 x 10,880 B

    int bid = blockIdx.x;
    int mt = 0;
    for (;;) {
        const int c = 12 - ((m0 + mt * 4) >> 5);
        if (bid < c) break;
        bid -= c; ++mt;
    }
    const int ltile = ((m0 + mt * 4) >> 5) + bid;
    const int l0 = ltile * 32;                  // even
    const int mb = m0 + mt * 4;

    const int tid  = threadIdx.x;
    const int wav  = tid >> 6;                  // 0..3 = m offset
    const int lane = tid & 63;
    const int r    = lane & 15;
    const int kg   = (lane >> 4) * 8;

    const int m    = mb + wav;
    const int mc   = (m < m_hi) ? m : (m_hi - 1);
    const int par  = mc & 1;
    const int mloc = mc - m0;

    const int srr = tid >> 2;
    const int sq  = (tid & 3) * 8;
    const int moff0 = srr >> 5,        loff0 = srr & 31;
    const int moff1 = (64 + srr) >> 5, loff1 = (64 + srr) & 31;
    int mst0 = mb + moff0; if (mst0 > MMAX - 1) mst0 = MMAX - 1;
    int mst1 = mb + moff1; if (mst1 > MMAX - 1) mst1 = MMAX - 1;
    int lst0 = l0 + loff0; if (lst0 > LMAX - 1) lst0 = LMAX - 1;
    int lst1 = l0 + loff1; if (lst1 > LMAX - 1) lst1 = LMAX - 1;
    const float* wsp0 = W + ((size_t)mst0 * LMAX + lst0) * NLAT + sq;
    const float* wsp1 = W + ((size_t)mst1 * LMAX + lst1) * NLAT + sq;
    const int ldso0 = ((moff0 * 2 + (loff0 & 1)) * 17 + (loff0 >> 1)) * 40 + sq;
    const int ldso1 = ((moff1 * 2 + (loff1 & 1)) * 17 + (loff1 >> 1)) * 40 + sq;

    const short* be0 = EO + (((size_t)mloc * 2 + 0) * NJ + r)      * KFP + kg;
    const short* be1 = EO + (((size_t)mloc * 2 + 0) * NJ + 16 + r) * KFP + kg;
    const short* bo0 = EO + (((size_t)mloc * 2 + 1) * NJ + r)      * KFP + kg;
    const short* bo1 = EO + (((size_t)mloc * 2 + 1) * NJ + 16 + r) * KFP + kg;

    const int aEo = ((wav * 2 + par) * 17 + r) * 40 + kg;
    const int aOo = ((wav * 2 + (1 - par)) * 17 + r) * 40 + kg;

    f32x4 accE0 = {0,0,0,0}, accE1 = {0,0,0,0}, accO0 = {0,0,0,0}, accO1 = {0,0,0,0};

    f32x4 Awa, Awb, Awc, Awd, Bwa, Bwb, Bwc, Bwd, Cwa, Cwb, Cwc, Cwd;
    bf16x8 Aba, Abb, Abc, Abd, Bba, Bbb, Bbc, Bbd, Cba, Cbb, Cbc, Cbd;

    S2_GW(A, 0); S2_GB(A, 0);
    S2_GW(B, 1); S2_GB(B, 1);
    S2_GW(C, 2); S2_GB(C, 2);

    S2_WRT(A, 0); S2_SYNC; S2_CMP(A, 0); S2_GW(A, 3); S2_GB(A, 3);
    S2_WRT(B, 1); S2_SYNC; S2_CMP(B, 1); S2_GW(B, 4); S2_GB(B, 4);
    S2_WRT(C, 0); S2_SYNC; S2_CMP(C, 0); S2_GW(C, 5); S2_GB(C, 5);
    S2_WRT(A, 1); S2_SYNC; S2_CMP(A, 1);
    S2_WRT(B, 0); S2_SYNC; S2_CMP(B, 0);
    S2_WRT(C, 1); S2_SYNC; S2_CMP(C, 1);

    const int rowg = (lane >> 4) * 4;
    if (m < m_hi) {
        #pragma unroll
        for (int i = 0; i < 4; ++i) {
            const int R  = rowg + i;
            const int le = l0 + par + 2 * R;
            const int lo = l0 + 1 - par + 2 * R;
            const size_t b0 = (size_t)r * LMAX;
            const size_t b1 = (size_t)(16 + r) * LMAX;
            if (le < LMAX) {
                out[(b0 + le) * MMAX + m] = accE0[i];
                out[(b1 + le) * MMAX + m] = accE1[i];
            }
            if (lo < LMAX) {
                out[(b0 + lo) * MMAX + m] = accO0[i];
                out[(b1 + lo) * MMAX + m] = accO1[i];
            }
        }
    }
}

extern "C" void kernel_launch(void* const* d_in, const int* in_sizes, int n_in,
                              void* d_out, int out_size, void* d_ws, size_t ws_size,
                              hipStream_t stream) {
    const float* x = (const float*)d_in[0];
    const float* w = (const float*)d_in[1];
    float* out = (float*)d_out;

    const size_t XR_OFF = (size_t)FT2R * FT2C * 2;   // 141,312 B
    const size_t PER_M  = (size_t)2 * NJ * KFP * 2;  // 24,576 B per mode
    long cm = 0;
    if (d_ws != nullptr && ws_size > XR_OFF + PER_M) cm = (long)((ws_size - XR_OFF) / PER_M);
    if (cm > MMAX) cm = MMAX;
    if (cm < 1) return;

    short* FT2 = (short*)d_ws;
    short* EO  = (short*)((char*)d_ws + XR_OFF);
    fill_ft_kernel<<<(FT2R * FT2C + 255) / 256, 256, 0, stream>>>(FT2);
    for (int m0 = 0; m0 < MMAX; m0 += (int)cm) {
        const int cmx = ((int)cm < MMAX - m0) ? (int)cm : (MMAX - m0);
        stage1_kernel<<<dim3(192), 512, 0, stream>>>(x, FT2, EO, m0, cmx);
        const int gym = (cmx + 3) / 4;
        int nblk = 0;
        for (int mtt = 0; mtt < gym; ++mtt) nblk += 12 - ((m0 + mtt * 4) >> 5);
        stage2_kernel<<<dim3(nblk), 256, 0, stream>>>(w, EO, out, m0, m0 + cmx);
    }
}